// Round 16
// baseline (273.576 us; speedup 1.0000x reference)
//
#include <hip/hip_runtime.h>

typedef unsigned short u16;
typedef unsigned int u32;
typedef __attribute__((ext_vector_type(8))) short bf16x8;
typedef __attribute__((ext_vector_type(4))) float f32x4;

#define MFMA(a, b, c) __builtin_amdgcn_mfma_f32_16x16x32_bf16((a), (b), (c), 0, 0, 0)

__device__ inline u16 f2bf(float f) {
  u32 u = __float_as_uint(f);
  u = (u + 0x7fffu + ((u >> 16) & 1u)) >> 16;
  return (u16)u;
}

__device__ inline void gld16(u16* lds, const u16* g) {
  __builtin_amdgcn_global_load_lds((const __attribute__((address_space(1))) void*)g,
                                   (__attribute__((address_space(3))) void*)lds,
                                   16, 0, 0);
}

// ---------------- fp32 -> bf16 convert (x + 4 weights in one launch) ----------------
__global__ __launch_bounds__(256) void cvt_all(const float* __restrict__ x,
                                               const float* __restrict__ wa,
                                               const float* __restrict__ wb,
                                               const float* __restrict__ wc,
                                               const float* __restrict__ wd,
                                               uint2* __restrict__ dst) {
  int i = blockIdx.x * 256 + threadIdx.x;  // f4 index, 6291456 total
  const float* s;
  int off;
  if (i < 2097152) {
    s = x; off = i;
  } else {
    int j = i - 2097152;
    int which = j >> 20;
    off = j & 1048575;
    s = (which == 0) ? wa : (which == 1) ? wb : (which == 2) ? wc : wd;
  }
  float4 f = ((const float4*)s)[off];
  u32 lo = (u32)f2bf(f.x) | ((u32)f2bf(f.y) << 16);
  u32 hi = (u32)f2bf(f.z) | ((u32)f2bf(f.w) << 16);
  dst[i] = make_uint2(lo, hi);
}

// ---------------- 128x128 GEMM core: C[m,n] = sum_k A[m,k] * W[n,k] ----------------
// 4-slot LDS rotation, one counted vmcnt(8)+barrier per K-tile, T2 involution swizzle.
__device__ inline void gemm_core(const u16* __restrict__ A, const u16* __restrict__ W,
                                 u16* As, u16* Bs, int m0, int n0, f32x4 acc[4][4]) {
  const int K = 2048;
  const int NT = 64;
  int t = threadIdx.x, w = t >> 6, l = t & 63;
  int wr = (w >> 1) * 64, wc = (w & 1) * 64;
  int fr = l & 15, fg = l >> 4;
  int r0 = t >> 2;
  int r1 = 64 + r0;
  int c00 = (t & 3) ^ ((r0 >> 1) & 3);
  int c01 = (t & 3) ^ ((r1 >> 1) & 3);
  const u16* gA = A + (size_t)m0 * K;
  const u16* gB = W + (size_t)n0 * K;
  size_t a0 = (size_t)r0 * K + c00 * 8;
  size_t a1 = (size_t)r1 * K + c01 * 8;
#pragma unroll
  for (int p = 0; p < 2; ++p) {  // prologue: stage tiles 0,1
    u16* sa = As + p * 4096;
    u16* sb = Bs + p * 4096;
    int kk = p * 32;
    gld16(sa + w * 512, gA + a0 + kk);
    gld16(sa + 2048 + w * 512, gA + a1 + kk);
    gld16(sb + w * 512, gB + a0 + kk);
    gld16(sb + 2048 + w * 512, gB + a1 + kk);
  }
  for (int kt = 0; kt < NT; ++kt) {
    int kt2 = (kt + 2 < NT) ? (kt + 2) : (NT - 1);  // clamped tail keeps vmcnt uniform
    u16* sa = As + ((kt + 2) & 3) * 4096;
    u16* sb = Bs + ((kt + 2) & 3) * 4096;
    int kk = kt2 * 32;
    gld16(sa + w * 512, gA + a0 + kk);
    gld16(sa + 2048 + w * 512, gA + a1 + kk);
    gld16(sb + w * 512, gB + a0 + kk);
    gld16(sb + 2048 + w * 512, gB + a1 + kk);
    asm volatile("s_waitcnt vmcnt(8)\n\ts_barrier" ::: "memory");
    const u16* ca = As + (kt & 3) * 4096;
    const u16* cb = Bs + (kt & 3) * 4096;
    bf16x8 af[4], bfv[4];
#pragma unroll
    for (int i = 0; i < 4; ++i) {
      int ar = wr + i * 16 + fr;
      af[i] = *(const bf16x8*)&ca[ar * 32 + ((fg ^ ((ar >> 1) & 3)) << 3)];
    }
#pragma unroll
    for (int i = 0; i < 4; ++i) {
      int br = wc + i * 16 + fr;
      bfv[i] = *(const bf16x8*)&cb[br * 32 + ((fg ^ ((br >> 1) & 3)) << 3)];
    }
    __builtin_amdgcn_s_setprio(1);
#pragma unroll
    for (int mi = 0; mi < 4; ++mi)
#pragma unroll
      for (int ni = 0; ni < 4; ++ni)
        acc[mi][ni] = MFMA(af[mi], bfv[ni], acc[mi][ni]);
    __builtin_amdgcn_s_setprio(0);
  }
}

// ---------------- Q,K projection: 256x256 tile, 8 waves (2Mx4N), BK=32, 4-slot ----------------
// Grid 16x16 = 256 blocks = exactly one dispatch round at 1 block/CU.
// Q,K -> [B,H,S,D]; Q pre-scaled by log2(e)/sqrt(128) (softmax in exp2 domain).
__global__ __launch_bounds__(512, 2) void qk_gemm(
    const u16* __restrict__ X, const u16* __restrict__ Wq, const u16* __restrict__ Wk,
    const float* __restrict__ bq, const float* __restrict__ bk, u16* __restrict__ Qo,
    u16* __restrict__ Ko) {
  __shared__ __attribute__((aligned(16))) u16 As[32768];  // 4 slots x 256x32, 64 KB
  __shared__ __attribute__((aligned(16))) u16 Bs[32768];  // 64 KB
  const int K = 2048, NT = 64;
  int which = blockIdx.x >> 3;
  int n0 = (blockIdx.x & 7) * 256;
  int m0 = blockIdx.y * 256;
  const u16* W = (which == 0) ? Wq : Wk;
  const float* bias = (which == 0) ? bq : bk;
  u16* out = (which == 0) ? Qo : Ko;
  float scale = (which == 0) ? 0.08838834764831845f * 1.4426950408889634f : 1.0f;
  int t = threadIdx.x, w = t >> 6, l = t & 63;
  int wm = w >> 2, wn = w & 3;               // wave tile: rows wm*128+[0,128), cols wn*64+[0,64)
  int fr = l & 15, fg = l >> 4;
  int r0 = t >> 2;                           // 0..127; second issue adds 128 rows
  int c0 = (t & 3) ^ ((r0 >> 1) & 3);        // involution slot (row+128 preserves (r>>1)&3)
  const u16* gA = X + (size_t)m0 * K;
  const u16* gB = W + (size_t)n0 * K;
  size_t a0 = (size_t)r0 * K + c0 * 8;
  size_t a1 = a0 + (size_t)128 * K;
  f32x4 zero4 = {0.f, 0.f, 0.f, 0.f};
  f32x4 acc[8][4];
#pragma unroll
  for (int i = 0; i < 8; ++i)
#pragma unroll
    for (int j = 0; j < 4; ++j) acc[i][j] = zero4;
#pragma unroll
  for (int p = 0; p < 2; ++p) {  // prologue: stage tiles 0,1
    u16* sa = As + p * 8192;
    u16* sb = Bs + p * 8192;
    int kk = p * 32;
    gld16(sa + w * 512, gA + a0 + kk);
    gld16(sa + 4096 + w * 512, gA + a1 + kk);
    gld16(sb + w * 512, gB + a0 + kk);
    gld16(sb + 4096 + w * 512, gB + a1 + kk);
  }
  for (int kt = 0; kt < NT; ++kt) {
    int kt2 = (kt + 2 < NT) ? (kt + 2) : (NT - 1);
    u16* sa = As + ((kt + 2) & 3) * 8192;
    u16* sb = Bs + ((kt + 2) & 3) * 8192;
    int kk = kt2 * 32;
    gld16(sa + w * 512, gA + a0 + kk);
    gld16(sa + 4096 + w * 512, gA + a1 + kk);
    gld16(sb + w * 512, gB + a0 + kk);
    gld16(sb + 4096 + w * 512, gB + a1 + kk);
    // 4 own loads/tile; own kt-group is 3rd-newest (<=12 outstanding) -> vmcnt(8)
    asm volatile("s_waitcnt vmcnt(8)\n\ts_barrier" ::: "memory");
    const u16* ca = As + (kt & 3) * 8192;
    const u16* cb = Bs + (kt & 3) * 8192;
    bf16x8 af[8], bfv[4];
#pragma unroll
    for (int i = 0; i < 8; ++i) {
      int ar = wm * 128 + i * 16 + fr;
      af[i] = *(const bf16x8*)&ca[ar * 32 + ((fg ^ ((ar >> 1) & 3)) << 3)];
    }
#pragma unroll
    for (int i = 0; i < 4; ++i) {
      int br = wn * 64 + i * 16 + fr;
      bfv[i] = *(const bf16x8*)&cb[br * 32 + ((fg ^ ((br >> 1) & 3)) << 3)];
    }
    __builtin_amdgcn_s_setprio(1);
#pragma unroll
    for (int mi = 0; mi < 8; ++mi)
#pragma unroll
      for (int ni = 0; ni < 4; ++ni)
        acc[mi][ni] = MFMA(af[mi], bfv[ni], acc[mi][ni]);
    __builtin_amdgcn_s_setprio(0);
  }
#pragma unroll
  for (int mi = 0; mi < 8; ++mi) {
#pragma unroll
    for (int ni = 0; ni < 4; ++ni) {
      int row = m0 + wm * 128 + mi * 16 + (l >> 4) * 4;
      int col = n0 + wn * 64 + ni * 16 + (l & 15);
      float bb = bias[col];
      int h = col >> 7, d = col & 127;
#pragma unroll
      for (int i = 0; i < 4; ++i) {
        int m = row + i;
        int b = m >> 11, s = m & 2047;
        float v = (acc[mi][ni][i] + bb) * scale;
        out[(((size_t)b * 16 + h) * 2048 + s) * 128 + d] = f2bf(v);
      }
    }
  }
}

// ---------------- V projection: 128x128 tile (proven gemm_core), V -> [B,H,D,S] ----------------
__global__ __launch_bounds__(256, 2) void v_gemm(const u16* __restrict__ X,
                                                 const u16* __restrict__ Wv,
                                                 const float* __restrict__ bv,
                                                 u16* __restrict__ Vo) {
  __shared__ __attribute__((aligned(16))) u16 As[16384];
  __shared__ __attribute__((aligned(16))) u16 Bs[16384];
  int n0 = blockIdx.x * 128, m0 = blockIdx.y * 128;
  f32x4 zero4 = {0.f, 0.f, 0.f, 0.f};
  f32x4 acc[4][4];
#pragma unroll
  for (int i = 0; i < 4; ++i)
#pragma unroll
    for (int j = 0; j < 4; ++j) acc[i][j] = zero4;
  gemm_core(X, Wv, As, Bs, m0, n0, acc);
  int t = threadIdx.x, w = t >> 6, l = t & 63;
  int wr = (w >> 1) * 64, wc = (w & 1) * 64;
  // V: transposed write [B,H,D,S]; 4 consecutive s per fragment -> one 8B store
#pragma unroll
  for (int mi = 0; mi < 4; ++mi) {
#pragma unroll
    for (int ni = 0; ni < 4; ++ni) {
      int row = m0 + wr + mi * 16 + (l >> 4) * 4;
      int col = n0 + wc + ni * 16 + (l & 15);
      float bb = bv[col];
      int h = col >> 7, d = col & 127;
      int b = row >> 11, s = row & 2047;
      u32 p0 = (u32)f2bf(acc[mi][ni][0] + bb) | ((u32)f2bf(acc[mi][ni][1] + bb) << 16);
      u32 p1 = (u32)f2bf(acc[mi][ni][2] + bb) | ((u32)f2bf(acc[mi][ni][3] + bb) << 16);
      *(uint2*)&Vo[((size_t)(b * 16 + h) * 128 + d) * 2048 + s] = make_uint2(p0, p1);
    }
  }
}

// ---------------- output projection (fp32 out + bias) ----------------
__global__ __launch_bounds__(256, 2) void oproj_gemm(const u16* __restrict__ A,
                                                     const u16* __restrict__ W,
                                                     const float* __restrict__ bias,
                                                     float* __restrict__ out) {
  __shared__ __attribute__((aligned(16))) u16 As[16384];
  __shared__ __attribute__((aligned(16))) u16 Bs[16384];
  int n0 = blockIdx.x * 128, m0 = blockIdx.y * 128;
  f32x4 zero4 = {0.f, 0.f, 0.f, 0.f};
  f32x4 acc[4][4];
#pragma unroll
  for (int i = 0; i < 4; ++i)
#pragma unroll
    for (int j = 0; j < 4; ++j) acc[i][j] = zero4;
  gemm_core(A, W, As, Bs, m0, n0, acc);
  int t = threadIdx.x, w = t >> 6, l = t & 63;
  int wr = (w >> 1) * 64, wc = (w & 1) * 64;
#pragma unroll
  for (int mi = 0; mi < 4; ++mi) {
#pragma unroll
    for (int ni = 0; ni < 4; ++ni) {
      int row = m0 + wr + mi * 16 + (l >> 4) * 4;
      int col = n0 + wc + ni * 16 + (l & 15);
      float bb = bias[col];
#pragma unroll
      for (int i = 0; i < 4; ++i) out[(size_t)(row + i) * 2048 + col] = acc[mi][ni][i] + bb;
    }
  }
}

// ---------------- flash attention (causal): 8 waves x 16 q-rows, KV tile 64 ----------------
// R14 structure (double-buffer + stage-ahead-1 + vmcnt(4), 512 threads, MFMA
// row-sum via lacc = mfma(P, ones, lacc)). Softmax in exp2 domain (log2e folded
// into Q scale) -- unconditional rescale, no branch (defer-max regressed, R12).
__global__ __launch_bounds__(512, 4) void attn_fwd(const u16* __restrict__ Q,
                                                   const u16* __restrict__ K,
                                                   const u16* __restrict__ Vt,
                                                   u16* __restrict__ AO) {
  __shared__ __attribute__((aligned(16))) u16 Ks[16384];   // 2 bufs x [64][128], 32 KB
  __shared__ __attribute__((aligned(16))) u16 Vts[16384];  // 2 bufs x [128][64], 32 KB
  __shared__ __attribute__((aligned(16))) u16 Pl[8192];    // 8 waves x [16][64], 16 KB
  const int D = 128;
  int b3 = blockIdx.x;
  int bh = b3 & 31;
  int xq = b3 >> 5;                          // 0..15
  int qt = (xq < 8) ? (15 - xq) : (xq - 8);  // paired: xq and xq+8 sum to const work
  int t = threadIdx.x, w = t >> 6, l = t & 63, g = l >> 4, c = l & 15;
  size_t base = (size_t)bh * 2048 * 128;
  const u16* Vbh = Vt + base;  // [128 d][2048 s]
  int q0 = qt * 128;
  int qrw = q0 + w * 16;  // 16 rows per wave
  // Q fragments in registers; Q pre-scaled by log2e/sqrt(D) in qk_gemm
  bf16x8 qf[4];
  {
    const u16* qp = Q + base + (size_t)(qrw + c) * D + g * 8;
#pragma unroll
    for (int ks = 0; ks < 4; ++ks) qf[ks] = *(const bf16x8*)(qp + ks * 32);
  }
  f32x4 zero4 = {0.f, 0.f, 0.f, 0.f};
  f32x4 oacc[8];
#pragma unroll
  for (int i = 0; i < 8; ++i) oacc[i] = zero4;
  f32x4 lacc = zero4;  // row sums via MFMA(P, ones)
  bf16x8 ones;
#pragma unroll
  for (int i = 0; i < 8; ++i) ones[i] = (short)0x3F80;  // bf16 1.0
  float mrow[4];
#pragma unroll
  for (int i = 0; i < 4; ++i) mrow[i] = -1e30f;
  char* pw = (char*)(Pl + w * 1024);  // per-wave [16][64] (2 KB)
  int ktmax = 2 * qt + 1;
  // staging: 4 gld16/thread/tile. K: lane task row=i*32+w*4+(l>>4), slot=l&15
  // holds global chunk slot^(row&7). V: vr=i*64+w*8+(l>>3), vslot=l&7 holds
  // chunk vslot^(vr&7). Dest bases wave-uniform; HW adds lane*16B.
#define STAGE_TILE(BUF, KV0)                                                          \
  {                                                                                   \
    _Pragma("unroll") for (int i = 0; i < 2; ++i) {                                   \
      int row = i * 32 + w * 4 + (l >> 4);                                            \
      int cc = (l & 15) ^ (row & 7);                                                  \
      gld16(Ks + (BUF)*8192 + i * 4096 + w * 512,                                     \
            K + base + (size_t)((KV0) + row) * D + cc * 8);                           \
    }                                                                                 \
    _Pragma("unroll") for (int i = 0; i < 2; ++i) {                                   \
      int vr = i * 64 + w * 8 + (l >> 3);                                             \
      int vslot = (l & 7) ^ ((l >> 3) & 7);                                           \
      gld16(Vts + (BUF)*8192 + i * 4096 + w * 512,                                    \
            Vbh + (size_t)vr * 2048 + (KV0) + vslot * 8);                             \
    }                                                                                 \
  }
  STAGE_TILE(0, 0)  // prologue: tile 0 -> buf 0
  for (int kt = 0; kt <= ktmax; ++kt) {
    int kv0 = kt * 64;
    int ktn = (kt + 1 <= ktmax) ? (kt + 1) : ktmax;  // clamped tail (uniform counts)
    STAGE_TILE((kt + 1) & 1, ktn * 64)
    // own tile-kt loads have exactly 4 newer (kt+1's) outstanding -> vmcnt(4)
    asm volatile("s_waitcnt vmcnt(4)\n\ts_barrier" ::: "memory");
    const u16* Kb = Ks + (kt & 1) * 8192;
    const u16* Vb2 = Vts + (kt & 1) * 8192;
    if (kv0 <= qrw + 15) {  // wave-uniform causal skip (no barriers inside)
      // ---- QK^T from LDS ----
      f32x4 sacc[4];
#pragma unroll
      for (int n = 0; n < 4; ++n) sacc[n] = zero4;
#pragma unroll
      for (int ks = 0; ks < 4; ++ks) {
#pragma unroll
        for (int n = 0; n < 4; ++n) {
          int row = n * 16 + c;
          bf16x8 kf = *(const bf16x8*)&Kb[row * 128 + (((ks * 4 + g) ^ (c & 7)) << 3)];
          sacc[n] = MFMA(qf[ks], kf, sacc[n]);
        }
      }
      float sc[4][4];
#pragma unroll
      for (int n = 0; n < 4; ++n)
#pragma unroll
        for (int i = 0; i < 4; ++i) sc[n][i] = sacc[n][i];
      if (kv0 + 63 > qrw) {  // diagonal region: causal mask
#pragma unroll
        for (int n = 0; n < 4; ++n) {
          int kv = kv0 + n * 16 + c;
#pragma unroll
          for (int i = 0; i < 4; ++i)
            if (kv > qrw + g * 4 + i) sc[n][i] = -1e30f;
        }
      }
      // ---- online softmax: max via 16-lane shuffle reduce; sum via MFMA below ----
      float tmax[4];
#pragma unroll
      for (int i = 0; i < 4; ++i)
        tmax[i] = fmaxf(fmaxf(sc[0][i], sc[1][i]), fmaxf(sc[2][i], sc[3][i]));
#pragma unroll
      for (int x = 1; x < 16; x <<= 1)
#pragma unroll
        for (int i = 0; i < 4; ++i) tmax[i] = fmaxf(tmax[i], __shfl_xor(tmax[i], x));
      float corr[4];
#pragma unroll
      for (int i = 0; i < 4; ++i) {
        float mn = fmaxf(mrow[i], tmax[i]);
        corr[i] = exp2f(mrow[i] - mn);
        mrow[i] = mn;
      }
#pragma unroll
      for (int i = 0; i < 4; ++i) lacc[i] *= corr[i];
#pragma unroll
      for (int nf = 0; nf < 8; ++nf)
#pragma unroll
        for (int i = 0; i < 4; ++i) oacc[nf][i] *= corr[i];
      float ps[4][4];
#pragma unroll
      for (int n = 0; n < 4; ++n)
#pragma unroll
        for (int i = 0; i < 4; ++i) ps[n][i] = exp2f(sc[n][i] - mrow[i]);
      // ---- P -> per-wave LDS (XOR-swizzled rows of 128B) ----
#pragma unroll
      for (int n = 0; n < 4; ++n)
#pragma unroll
        for (int i = 0; i < 4; ++i) {
          int row = g * 4 + i;
          *(u16*)(pw + row * 128 + ((n * 32 + c * 2) ^ ((row & 7) << 4))) = f2bf(ps[n][i]);
        }
      // ---- PV + row-sum: B-fragments from swizzled Vts; lacc += P . ones ----
#pragma unroll
      for (int ks = 0; ks < 2; ++ks) {
        bf16x8 pf = *(const bf16x8*)(pw + c * 128 + ((ks * 64 + g * 16) ^ ((c & 7) << 4)));
        lacc = MFMA(pf, ones, lacc);  // lacc[i] += sum_kv P[g*4+i][kv in this ks]
#pragma unroll
        for (int nf = 0; nf < 8; ++nf) {
          bf16x8 vf = *(const bf16x8*)&Vb2[(nf * 16 + c) * 64 + (((ks * 4 + g) ^ (c & 7)) << 3)];
          oacc[nf] = MFMA(pf, vf, oacc[nf]);
        }
      }
    }
    __syncthreads();  // compute-kt LDS reads done before kt+2 overwrites buf[kt&1]
  }
  int b = bh >> 4, h = bh & 15;
#pragma unroll
  for (int nf = 0; nf < 8; ++nf) {
    int d = h * 128 + nf * 16 + c;
#pragma unroll
    for (int i = 0; i < 4; ++i) {
      int q = qrw + g * 4 + i;
      AO[((size_t)b * 2048 + q) * 2048 + d] = f2bf(oacc[nf][i] / lacc[i]);
    }
  }
}

extern "C" void kernel_launch(void* const* d_in, const int* in_sizes, int n_in,
                              void* d_out, int out_size, void* d_ws, size_t ws_size,
                              hipStream_t stream) {
  const float* x = (const float*)d_in[0];
  const float* Wq = (const float*)d_in[1];
  const float* bq = (const float*)d_in[2];
  const float* Wk = (const float*)d_in[3];
  const float* bk = (const float*)d_in[4];
  const float* Wv = (const float*)d_in[5];
  const float* bv = (const float*)d_in[6];
  const float* Wo = (const float*)d_in[7];
  const float* bo = (const float*)d_in[8];
  float* out = (float*)d_out;

  u16* xb = (u16*)d_ws;
  u16* Wqb = xb + 8388608;
  u16* Wkb = Wqb + 4194304;
  u16* Wvb = Wkb + 4194304;
  u16* Wob = Wvb + 4194304;
  u16* Qb = Wob + 4194304;
  u16* Kb = Qb + 8388608;
  u16* Vb = Kb + 8388608;  // [B,H,D,S] transposed
  u16* AOb = xb;           // alias: x_bf16 dead after projections

  cvt_all<<<24576, 256, 0, stream>>>(x, Wq, Wk, Wv, Wo, (uint2*)d_ws);
  qk_gemm<<<dim3(16, 16), 512, 0, stream>>>(xb, Wqb, Wkb, bq, bk, Qb, Kb);
  v_gemm<<<dim3(16, 32), 256, 0, stream>>>(xb, Wvb, bv, Vb);
  attn_fwd<<<512, 512, 0, stream>>>(Qb, Kb, Vb, AOb);
  oproj_gemm<<<dim3(16, 32), 256, 0, stream>>>(AOb, Wob, bo, out);
}

// Round 17
// 259.242 us; speedup vs baseline: 1.0553x; 1.0553x over previous
//
#include <hip/hip_runtime.h>

typedef unsigned short u16;
typedef unsigned int u32;
typedef __attribute__((ext_vector_type(8))) short bf16x8;
typedef __attribute__((ext_vector_type(4))) float f32x4;

#define MFMA(a, b, c) __builtin_amdgcn_mfma_f32_16x16x32_bf16((a), (b), (c), 0, 0, 0)

__device__ inline u16 f2bf(float f) {
  u32 u = __float_as_uint(f);
  u = (u + 0x7fffu + ((u >> 16) & 1u)) >> 16;
  return (u16)u;
}

__device__ inline void gld16(u16* lds, const u16* g) {
  __builtin_amdgcn_global_load_lds((const __attribute__((address_space(1))) void*)g,
                                   (__attribute__((address_space(3))) void*)lds,
                                   16, 0, 0);
}

// ---------------- fp32 -> bf16 convert (x + 4 weights in one launch) ----------------
__global__ __launch_bounds__(256) void cvt_all(const float* __restrict__ x,
                                               const float* __restrict__ wa,
                                               const float* __restrict__ wb,
                                               const float* __restrict__ wc,
                                               const float* __restrict__ wd,
                                               uint2* __restrict__ dst) {
  int i = blockIdx.x * 256 + threadIdx.x;  // f4 index, 6291456 total
  const float* s;
  int off;
  if (i < 2097152) {
    s = x; off = i;
  } else {
    int j = i - 2097152;
    int which = j >> 20;
    off = j & 1048575;
    s = (which == 0) ? wa : (which == 1) ? wb : (which == 2) ? wc : wd;
  }
  float4 f = ((const float4*)s)[off];
  u32 lo = (u32)f2bf(f.x) | ((u32)f2bf(f.y) << 16);
  u32 hi = (u32)f2bf(f.z) | ((u32)f2bf(f.w) << 16);
  dst[i] = make_uint2(lo, hi);
}

// ---------------- 128x128 GEMM core: C[m,n] = sum_k A[m,k] * W[n,k] ----------------
// 4-slot LDS rotation, one counted vmcnt(8)+barrier per K-tile, T2 involution swizzle.
__device__ inline void gemm_core(const u16* __restrict__ A, const u16* __restrict__ W,
                                 u16* As, u16* Bs, int m0, int n0, f32x4 acc[4][4]) {
  const int K = 2048;
  const int NT = 64;
  int t = threadIdx.x, w = t >> 6, l = t & 63;
  int wr = (w >> 1) * 64, wc = (w & 1) * 64;
  int fr = l & 15, fg = l >> 4;
  int r0 = t >> 2;
  int r1 = 64 + r0;
  int c00 = (t & 3) ^ ((r0 >> 1) & 3);
  int c01 = (t & 3) ^ ((r1 >> 1) & 3);
  const u16* gA = A + (size_t)m0 * K;
  const u16* gB = W + (size_t)n0 * K;
  size_t a0 = (size_t)r0 * K + c00 * 8;
  size_t a1 = (size_t)r1 * K + c01 * 8;
#pragma unroll
  for (int p = 0; p < 2; ++p) {  // prologue: stage tiles 0,1
    u16* sa = As + p * 4096;
    u16* sb = Bs + p * 4096;
    int kk = p * 32;
    gld16(sa + w * 512, gA + a0 + kk);
    gld16(sa + 2048 + w * 512, gA + a1 + kk);
    gld16(sb + w * 512, gB + a0 + kk);
    gld16(sb + 2048 + w * 512, gB + a1 + kk);
  }
  for (int kt = 0; kt < NT; ++kt) {
    int kt2 = (kt + 2 < NT) ? (kt + 2) : (NT - 1);  // clamped tail keeps vmcnt uniform
    u16* sa = As + ((kt + 2) & 3) * 4096;
    u16* sb = Bs + ((kt + 2) & 3) * 4096;
    int kk = kt2 * 32;
    gld16(sa + w * 512, gA + a0 + kk);
    gld16(sa + 2048 + w * 512, gA + a1 + kk);
    gld16(sb + w * 512, gB + a0 + kk);
    gld16(sb + 2048 + w * 512, gB + a1 + kk);
    asm volatile("s_waitcnt vmcnt(8)\n\ts_barrier" ::: "memory");
    const u16* ca = As + (kt & 3) * 4096;
    const u16* cb = Bs + (kt & 3) * 4096;
    bf16x8 af[4], bfv[4];
#pragma unroll
    for (int i = 0; i < 4; ++i) {
      int ar = wr + i * 16 + fr;
      af[i] = *(const bf16x8*)&ca[ar * 32 + ((fg ^ ((ar >> 1) & 3)) << 3)];
    }
#pragma unroll
    for (int i = 0; i < 4; ++i) {
      int br = wc + i * 16 + fr;
      bfv[i] = *(const bf16x8*)&cb[br * 32 + ((fg ^ ((br >> 1) & 3)) << 3)];
    }
    __builtin_amdgcn_s_setprio(1);
#pragma unroll
    for (int mi = 0; mi < 4; ++mi)
#pragma unroll
      for (int ni = 0; ni < 4; ++ni)
        acc[mi][ni] = MFMA(af[mi], bfv[ni], acc[mi][ni]);
    __builtin_amdgcn_s_setprio(0);
  }
}

// ---------------- Q,K projection: 256x256 tile, 8 waves (2Mx4N), BK=32, 4-slot ----------------
// Grid 16x16 = 256 blocks = exactly one dispatch round at 1 block/CU.
// Q,K -> [B,H,S,D]; Q pre-scaled by 1/sqrt(128).
__global__ __launch_bounds__(512, 2) void qk_gemm(
    const u16* __restrict__ X, const u16* __restrict__ Wq, const u16* __restrict__ Wk,
    const float* __restrict__ bq, const float* __restrict__ bk, u16* __restrict__ Qo,
    u16* __restrict__ Ko) {
  __shared__ __attribute__((aligned(16))) u16 As[32768];  // 4 slots x 256x32, 64 KB
  __shared__ __attribute__((aligned(16))) u16 Bs[32768];  // 64 KB
  const int K = 2048, NT = 64;
  int which = blockIdx.x >> 3;
  int n0 = (blockIdx.x & 7) * 256;
  int m0 = blockIdx.y * 256;
  const u16* W = (which == 0) ? Wq : Wk;
  const float* bias = (which == 0) ? bq : bk;
  u16* out = (which == 0) ? Qo : Ko;
  float scale = (which == 0) ? 0.08838834764831845f : 1.0f;
  int t = threadIdx.x, w = t >> 6, l = t & 63;
  int wm = w >> 2, wn = w & 3;               // wave tile: rows wm*128+[0,128), cols wn*64+[0,64)
  int fr = l & 15, fg = l >> 4;
  int r0 = t >> 2;                           // 0..127; second issue adds 128 rows
  int c0 = (t & 3) ^ ((r0 >> 1) & 3);        // involution slot (row+128 preserves (r>>1)&3)
  const u16* gA = X + (size_t)m0 * K;
  const u16* gB = W + (size_t)n0 * K;
  size_t a0 = (size_t)r0 * K + c0 * 8;
  size_t a1 = a0 + (size_t)128 * K;
  f32x4 zero4 = {0.f, 0.f, 0.f, 0.f};
  f32x4 acc[8][4];
#pragma unroll
  for (int i = 0; i < 8; ++i)
#pragma unroll
    for (int j = 0; j < 4; ++j) acc[i][j] = zero4;
#pragma unroll
  for (int p = 0; p < 2; ++p) {  // prologue: stage tiles 0,1
    u16* sa = As + p * 8192;
    u16* sb = Bs + p * 8192;
    int kk = p * 32;
    gld16(sa + w * 512, gA + a0 + kk);
    gld16(sa + 4096 + w * 512, gA + a1 + kk);
    gld16(sb + w * 512, gB + a0 + kk);
    gld16(sb + 4096 + w * 512, gB + a1 + kk);
  }
  for (int kt = 0; kt < NT; ++kt) {
    int kt2 = (kt + 2 < NT) ? (kt + 2) : (NT - 1);
    u16* sa = As + ((kt + 2) & 3) * 8192;
    u16* sb = Bs + ((kt + 2) & 3) * 8192;
    int kk = kt2 * 32;
    gld16(sa + w * 512, gA + a0 + kk);
    gld16(sa + 4096 + w * 512, gA + a1 + kk);
    gld16(sb + w * 512, gB + a0 + kk);
    gld16(sb + 4096 + w * 512, gB + a1 + kk);
    // 4 own loads/tile; own kt-group is 3rd-newest (<=12 outstanding) -> vmcnt(8)
    asm volatile("s_waitcnt vmcnt(8)\n\ts_barrier" ::: "memory");
    const u16* ca = As + (kt & 3) * 8192;
    const u16* cb = Bs + (kt & 3) * 8192;
    bf16x8 af[8], bfv[4];
#pragma unroll
    for (int i = 0; i < 8; ++i) {
      int ar = wm * 128 + i * 16 + fr;
      af[i] = *(const bf16x8*)&ca[ar * 32 + ((fg ^ ((ar >> 1) & 3)) << 3)];
    }
#pragma unroll
    for (int i = 0; i < 4; ++i) {
      int br = wn * 64 + i * 16 + fr;
      bfv[i] = *(const bf16x8*)&cb[br * 32 + ((fg ^ ((br >> 1) & 3)) << 3)];
    }
    __builtin_amdgcn_s_setprio(1);
#pragma unroll
    for (int mi = 0; mi < 8; ++mi)
#pragma unroll
      for (int ni = 0; ni < 4; ++ni)
        acc[mi][ni] = MFMA(af[mi], bfv[ni], acc[mi][ni]);
    __builtin_amdgcn_s_setprio(0);
  }
#pragma unroll
  for (int mi = 0; mi < 8; ++mi) {
#pragma unroll
    for (int ni = 0; ni < 4; ++ni) {
      int row = m0 + wm * 128 + mi * 16 + (l >> 4) * 4;
      int col = n0 + wn * 64 + ni * 16 + (l & 15);
      float bb = bias[col];
      int h = col >> 7, d = col & 127;
#pragma unroll
      for (int i = 0; i < 4; ++i) {
        int m = row + i;
        int b = m >> 11, s = m & 2047;
        float v = (acc[mi][ni][i] + bb) * scale;
        out[(((size_t)b * 16 + h) * 2048 + s) * 128 + d] = f2bf(v);
      }
    }
  }
}

// ---------------- V projection: 128x128 tile (proven gemm_core), V -> [B,H,D,S] ----------------
__global__ __launch_bounds__(256, 2) void v_gemm(const u16* __restrict__ X,
                                                 const u16* __restrict__ Wv,
                                                 const float* __restrict__ bv,
                                                 u16* __restrict__ Vo) {
  __shared__ __attribute__((aligned(16))) u16 As[16384];
  __shared__ __attribute__((aligned(16))) u16 Bs[16384];
  int n0 = blockIdx.x * 128, m0 = blockIdx.y * 128;
  f32x4 zero4 = {0.f, 0.f, 0.f, 0.f};
  f32x4 acc[4][4];
#pragma unroll
  for (int i = 0; i < 4; ++i)
#pragma unroll
    for (int j = 0; j < 4; ++j) acc[i][j] = zero4;
  gemm_core(X, Wv, As, Bs, m0, n0, acc);
  int t = threadIdx.x, w = t >> 6, l = t & 63;
  int wr = (w >> 1) * 64, wc = (w & 1) * 64;
  // V: transposed write [B,H,D,S]; 4 consecutive s per fragment -> one 8B store
#pragma unroll
  for (int mi = 0; mi < 4; ++mi) {
#pragma unroll
    for (int ni = 0; ni < 4; ++ni) {
      int row = m0 + wr + mi * 16 + (l >> 4) * 4;
      int col = n0 + wc + ni * 16 + (l & 15);
      float bb = bv[col];
      int h = col >> 7, d = col & 127;
      int b = row >> 11, s = row & 2047;
      u32 p0 = (u32)f2bf(acc[mi][ni][0] + bb) | ((u32)f2bf(acc[mi][ni][1] + bb) << 16);
      u32 p1 = (u32)f2bf(acc[mi][ni][2] + bb) | ((u32)f2bf(acc[mi][ni][3] + bb) << 16);
      *(uint2*)&Vo[((size_t)(b * 16 + h) * 128 + d) * 2048 + s] = make_uint2(p0, p1);
    }
  }
}

// ---------------- output projection (fp32 out + bias) ----------------
__global__ __launch_bounds__(256, 2) void oproj_gemm(const u16* __restrict__ A,
                                                     const u16* __restrict__ W,
                                                     const float* __restrict__ bias,
                                                     float* __restrict__ out) {
  __shared__ __attribute__((aligned(16))) u16 As[16384];
  __shared__ __attribute__((aligned(16))) u16 Bs[16384];
  int n0 = blockIdx.x * 128, m0 = blockIdx.y * 128;
  f32x4 zero4 = {0.f, 0.f, 0.f, 0.f};
  f32x4 acc[4][4];
#pragma unroll
  for (int i = 0; i < 4; ++i)
#pragma unroll
    for (int j = 0; j < 4; ++j) acc[i][j] = zero4;
  gemm_core(A, W, As, Bs, m0, n0, acc);
  int t = threadIdx.x, w = t >> 6, l = t & 63;
  int wr = (w >> 1) * 64, wc = (w & 1) * 64;
#pragma unroll
  for (int mi = 0; mi < 4; ++mi) {
#pragma unroll
    for (int ni = 0; ni < 4; ++ni) {
      int row = m0 + wr + mi * 16 + (l >> 4) * 4;
      int col = n0 + wc + ni * 16 + (l & 15);
      float bb = bias[col];
#pragma unroll
      for (int i = 0; i < 4; ++i) out[(size_t)(row + i) * 2048 + col] = acc[mi][ni][i] + bb;
    }
  }
}

// ---------------- flash attention (causal): 8 waves x 16 q-rows, KV tile 64 ----------------
// Proven R14 structure: double-buffer + stage-ahead-1 + counted vmcnt(4), 512
// threads, MFMA row-sum (lacc = mfma(P, ones, lacc)), plain __expf softmax
// (exp2f regressed: precise libm path without fast-math; __expf = v_exp_f32).
__global__ __launch_bounds__(512, 4) void attn_fwd(const u16* __restrict__ Q,
                                                   const u16* __restrict__ K,
                                                   const u16* __restrict__ Vt,
                                                   u16* __restrict__ AO) {
  __shared__ __attribute__((aligned(16))) u16 Ks[16384];   // 2 bufs x [64][128], 32 KB
  __shared__ __attribute__((aligned(16))) u16 Vts[16384];  // 2 bufs x [128][64], 32 KB
  __shared__ __attribute__((aligned(16))) u16 Pl[8192];    // 8 waves x [16][64], 16 KB
  const int D = 128;
  int b3 = blockIdx.x;
  int bh = b3 & 31;
  int xq = b3 >> 5;                          // 0..15
  int qt = (xq < 8) ? (15 - xq) : (xq - 8);  // paired: xq and xq+8 sum to const work
  int t = threadIdx.x, w = t >> 6, l = t & 63, g = l >> 4, c = l & 15;
  size_t base = (size_t)bh * 2048 * 128;
  const u16* Vbh = Vt + base;  // [128 d][2048 s]
  int q0 = qt * 128;
  int qrw = q0 + w * 16;  // 16 rows per wave
  // Q fragments in registers; Q pre-scaled by 1/sqrt(D) in qk_gemm
  bf16x8 qf[4];
  {
    const u16* qp = Q + base + (size_t)(qrw + c) * D + g * 8;
#pragma unroll
    for (int ks = 0; ks < 4; ++ks) qf[ks] = *(const bf16x8*)(qp + ks * 32);
  }
  f32x4 zero4 = {0.f, 0.f, 0.f, 0.f};
  f32x4 oacc[8];
#pragma unroll
  for (int i = 0; i < 8; ++i) oacc[i] = zero4;
  f32x4 lacc = zero4;  // row sums via MFMA(P, ones)
  bf16x8 ones;
#pragma unroll
  for (int i = 0; i < 8; ++i) ones[i] = (short)0x3F80;  // bf16 1.0
  float mrow[4];
#pragma unroll
  for (int i = 0; i < 4; ++i) mrow[i] = -1e30f;
  char* pw = (char*)(Pl + w * 1024);  // per-wave [16][64] (2 KB)
  int ktmax = 2 * qt + 1;
  // staging: 4 gld16/thread/tile. K: lane task row=i*32+w*4+(l>>4), slot=l&15
  // holds global chunk slot^(row&7). V: vr=i*64+w*8+(l>>3), vslot=l&7 holds
  // chunk vslot^(vr&7). Dest bases wave-uniform; HW adds lane*16B.
#define STAGE_TILE(BUF, KV0)                                                          \
  {                                                                                   \
    _Pragma("unroll") for (int i = 0; i < 2; ++i) {                                   \
      int row = i * 32 + w * 4 + (l >> 4);                                            \
      int cc = (l & 15) ^ (row & 7);                                                  \
      gld16(Ks + (BUF)*8192 + i * 4096 + w * 512,                                     \
            K + base + (size_t)((KV0) + row) * D + cc * 8);                           \
    }                                                                                 \
    _Pragma("unroll") for (int i = 0; i < 2; ++i) {                                   \
      int vr = i * 64 + w * 8 + (l >> 3);                                             \
      int vslot = (l & 7) ^ ((l >> 3) & 7);                                           \
      gld16(Vts + (BUF)*8192 + i * 4096 + w * 512,                                    \
            Vbh + (size_t)vr * 2048 + (KV0) + vslot * 8);                             \
    }                                                                                 \
  }
  STAGE_TILE(0, 0)  // prologue: tile 0 -> buf 0
  for (int kt = 0; kt <= ktmax; ++kt) {
    int kv0 = kt * 64;
    int ktn = (kt + 1 <= ktmax) ? (kt + 1) : ktmax;  // clamped tail (uniform counts)
    STAGE_TILE((kt + 1) & 1, ktn * 64)
    // own tile-kt loads have exactly 4 newer (kt+1's) outstanding -> vmcnt(4)
    asm volatile("s_waitcnt vmcnt(4)\n\ts_barrier" ::: "memory");
    const u16* Kb = Ks + (kt & 1) * 8192;
    const u16* Vb2 = Vts + (kt & 1) * 8192;
    if (kv0 <= qrw + 15) {  // wave-uniform causal skip (no barriers inside)
      // ---- QK^T from LDS ----
      f32x4 sacc[4];
#pragma unroll
      for (int n = 0; n < 4; ++n) sacc[n] = zero4;
#pragma unroll
      for (int ks = 0; ks < 4; ++ks) {
#pragma unroll
        for (int n = 0; n < 4; ++n) {
          int row = n * 16 + c;
          bf16x8 kf = *(const bf16x8*)&Kb[row * 128 + (((ks * 4 + g) ^ (c & 7)) << 3)];
          sacc[n] = MFMA(qf[ks], kf, sacc[n]);
        }
      }
      float sc[4][4];
#pragma unroll
      for (int n = 0; n < 4; ++n)
#pragma unroll
        for (int i = 0; i < 4; ++i) sc[n][i] = sacc[n][i];
      if (kv0 + 63 > qrw) {  // diagonal region: causal mask
#pragma unroll
        for (int n = 0; n < 4; ++n) {
          int kv = kv0 + n * 16 + c;
#pragma unroll
          for (int i = 0; i < 4; ++i)
            if (kv > qrw + g * 4 + i) sc[n][i] = -1e30f;
        }
      }
      // ---- online softmax: max via 16-lane shuffle reduce; sum via MFMA below ----
      float tmax[4];
#pragma unroll
      for (int i = 0; i < 4; ++i)
        tmax[i] = fmaxf(fmaxf(sc[0][i], sc[1][i]), fmaxf(sc[2][i], sc[3][i]));
#pragma unroll
      for (int x = 1; x < 16; x <<= 1)
#pragma unroll
        for (int i = 0; i < 4; ++i) tmax[i] = fmaxf(tmax[i], __shfl_xor(tmax[i], x));
      float corr[4];
#pragma unroll
      for (int i = 0; i < 4; ++i) {
        float mn = fmaxf(mrow[i], tmax[i]);
        corr[i] = __expf(mrow[i] - mn);
        mrow[i] = mn;
      }
#pragma unroll
      for (int i = 0; i < 4; ++i) lacc[i] *= corr[i];
#pragma unroll
      for (int nf = 0; nf < 8; ++nf)
#pragma unroll
        for (int i = 0; i < 4; ++i) oacc[nf][i] *= corr[i];
      float ps[4][4];
#pragma unroll
      for (int n = 0; n < 4; ++n)
#pragma unroll
        for (int i = 0; i < 4; ++i) ps[n][i] = __expf(sc[n][i] - mrow[i]);
      // ---- P -> per-wave LDS (XOR-swizzled rows of 128B) ----
#pragma unroll
      for (int n = 0; n < 4; ++n)
#pragma unroll
        for (int i = 0; i < 4; ++i) {
          int row = g * 4 + i;
          *(u16*)(pw + row * 128 + ((n * 32 + c * 2) ^ ((row & 7) << 4))) = f2bf(ps[n][i]);
        }
      // ---- PV + row-sum: B-fragments from swizzled Vts; lacc += P . ones ----
#pragma unroll
      for (int ks = 0; ks < 2; ++ks) {
        bf16x8 pf = *(const bf16x8*)(pw + c * 128 + ((ks * 64 + g * 16) ^ ((c & 7) << 4)));
        lacc = MFMA(pf, ones, lacc);  // lacc[i] += sum_kv P[g*4+i][kv in this ks]
#pragma unroll
        for (int nf = 0; nf < 8; ++nf) {
          bf16x8 vf = *(const bf16x8*)&Vb2[(nf * 16 + c) * 64 + (((ks * 4 + g) ^ (c & 7)) << 3)];
          oacc[nf] = MFMA(pf, vf, oacc[nf]);
        }
      }
    }
    __syncthreads();  // compute-kt LDS reads done before kt+2 overwrites buf[kt&1]
  }
  int b = bh >> 4, h = bh & 15;
#pragma unroll
  for (int nf = 0; nf < 8; ++nf) {
    int d = h * 128 + nf * 16 + c;
#pragma unroll
    for (int i = 0; i < 4; ++i) {
      int q = qrw + g * 4 + i;
      AO[((size_t)b * 2048 + q) * 2048 + d] = f2bf(oacc[nf][i] / lacc[i]);
    }
  }
}

extern "C" void kernel_launch(void* const* d_in, const int* in_sizes, int n_in,
                              void* d_out, int out_size, void* d_ws, size_t ws_size,
                              hipStream_t stream) {
  const float* x = (const float*)d_in[0];
  const float* Wq = (const float*)d_in[1];
  const float* bq = (const float*)d_in[2];
  const float* Wk = (const float*)d_in[3];
  const float* bk = (const float*)d_in[4];
  const float* Wv = (const float*)d_in[5];
  const float* bv = (const float*)d_in[6];
  const float* Wo = (const float*)d_in[7];
  const float* bo = (const float*)d_in[8];
  float* out = (float*)d_out;

  u16* xb = (u16*)d_ws;
  u16* Wqb = xb + 8388608;
  u16* Wkb = Wqb + 4194304;
  u16* Wvb = Wkb + 4194304;
  u16* Wob = Wvb + 4194304;
  u16* Qb = Wob + 4194304;
  u16* Kb = Qb + 8388608;
  u16* Vb = Kb + 8388608;  // [B,H,D,S] transposed
  u16* AOb = xb;           // alias: x_bf16 dead after projections

  cvt_all<<<24576, 256, 0, stream>>>(x, Wq, Wk, Wv, Wo, (uint2*)d_ws);
  qk_gemm<<<dim3(16, 16), 512, 0, stream>>>(xb, Wqb, Wkb, bq, bk, Qb, Kb);
  v_gemm<<<dim3(16, 32), 256, 0, stream>>>(xb, Wvb, bv, Vb);
  attn_fwd<<<512, 512, 0, stream>>>(Qb, Kb, Vb, AOb);
  oproj_gemm<<<dim3(16, 32), 256, 0, stream>>>(AOb, Wob, bo, out);
}

// Round 18
// 256.809 us; speedup vs baseline: 1.0653x; 1.0095x over previous
//
#include <hip/hip_runtime.h>

typedef unsigned short u16;
typedef unsigned int u32;
typedef __attribute__((ext_vector_type(8))) short bf16x8;
typedef __attribute__((ext_vector_type(4))) float f32x4;

#define MFMA(a, b, c) __builtin_amdgcn_mfma_f32_16x16x32_bf16((a), (b), (c), 0, 0, 0)

__device__ inline u16 f2bf(float f) {
  u32 u = __float_as_uint(f);
  u = (u + 0x7fffu + ((u >> 16) & 1u)) >> 16;
  return (u16)u;
}

__device__ inline void gld16(u16* lds, const u16* g) {
  __builtin_amdgcn_global_load_lds((const __attribute__((address_space(1))) void*)g,
                                   (__attribute__((address_space(3))) void*)lds,
                                   16, 0, 0);
}

// ---------------- fp32 -> bf16 convert (x + 4 weights in one launch) ----------------
__global__ __launch_bounds__(256) void cvt_all(const float* __restrict__ x,
                                               const float* __restrict__ wa,
                                               const float* __restrict__ wb,
                                               const float* __restrict__ wc,
                                               const float* __restrict__ wd,
                                               uint2* __restrict__ dst) {
  int i = blockIdx.x * 256 + threadIdx.x;  // f4 index, 6291456 total
  const float* s;
  int off;
  if (i < 2097152) {
    s = x; off = i;
  } else {
    int j = i - 2097152;
    int which = j >> 20;
    off = j & 1048575;
    s = (which == 0) ? wa : (which == 1) ? wb : (which == 2) ? wc : wd;
  }
  float4 f = ((const float4*)s)[off];
  u32 lo = (u32)f2bf(f.x) | ((u32)f2bf(f.y) << 16);
  u32 hi = (u32)f2bf(f.z) | ((u32)f2bf(f.w) << 16);
  dst[i] = make_uint2(lo, hi);
}

// ---------------- 128x128 GEMM core: C[m,n] = sum_k A[m,k] * W[n,k] ----------------
// 4-slot LDS rotation, one counted vmcnt(8)+barrier per K-tile, T2 involution swizzle.
__device__ inline void gemm_core(const u16* __restrict__ A, const u16* __restrict__ W,
                                 u16* As, u16* Bs, int m0, int n0, f32x4 acc[4][4]) {
  const int K = 2048;
  const int NT = 64;
  int t = threadIdx.x, w = t >> 6, l = t & 63;
  int wr = (w >> 1) * 64, wc = (w & 1) * 64;
  int fr = l & 15, fg = l >> 4;
  int r0 = t >> 2;
  int r1 = 64 + r0;
  int c00 = (t & 3) ^ ((r0 >> 1) & 3);
  int c01 = (t & 3) ^ ((r1 >> 1) & 3);
  const u16* gA = A + (size_t)m0 * K;
  const u16* gB = W + (size_t)n0 * K;
  size_t a0 = (size_t)r0 * K + c00 * 8;
  size_t a1 = (size_t)r1 * K + c01 * 8;
#pragma unroll
  for (int p = 0; p < 2; ++p) {  // prologue: stage tiles 0,1
    u16* sa = As + p * 4096;
    u16* sb = Bs + p * 4096;
    int kk = p * 32;
    gld16(sa + w * 512, gA + a0 + kk);
    gld16(sa + 2048 + w * 512, gA + a1 + kk);
    gld16(sb + w * 512, gB + a0 + kk);
    gld16(sb + 2048 + w * 512, gB + a1 + kk);
  }
  for (int kt = 0; kt < NT; ++kt) {
    int kt2 = (kt + 2 < NT) ? (kt + 2) : (NT - 1);  // clamped tail keeps vmcnt uniform
    u16* sa = As + ((kt + 2) & 3) * 4096;
    u16* sb = Bs + ((kt + 2) & 3) * 4096;
    int kk = kt2 * 32;
    gld16(sa + w * 512, gA + a0 + kk);
    gld16(sa + 2048 + w * 512, gA + a1 + kk);
    gld16(sb + w * 512, gB + a0 + kk);
    gld16(sb + 2048 + w * 512, gB + a1 + kk);
    asm volatile("s_waitcnt vmcnt(8)\n\ts_barrier" ::: "memory");
    const u16* ca = As + (kt & 3) * 4096;
    const u16* cb = Bs + (kt & 3) * 4096;
    bf16x8 af[4], bfv[4];
#pragma unroll
    for (int i = 0; i < 4; ++i) {
      int ar = wr + i * 16 + fr;
      af[i] = *(const bf16x8*)&ca[ar * 32 + ((fg ^ ((ar >> 1) & 3)) << 3)];
    }
#pragma unroll
    for (int i = 0; i < 4; ++i) {
      int br = wc + i * 16 + fr;
      bfv[i] = *(const bf16x8*)&cb[br * 32 + ((fg ^ ((br >> 1) & 3)) << 3)];
    }
    __builtin_amdgcn_s_setprio(1);
#pragma unroll
    for (int mi = 0; mi < 4; ++mi)
#pragma unroll
      for (int ni = 0; ni < 4; ++ni)
        acc[mi][ni] = MFMA(af[mi], bfv[ni], acc[mi][ni]);
    __builtin_amdgcn_s_setprio(0);
  }
}

// ---------------- Q,K projection: 256x256 tile, 8 waves (2Mx4N), BK=32, 4-slot ----------------
// Grid 16x16 = 256 blocks = exactly one dispatch round at 1 block/CU.
// Q,K -> [B,H,S,D]; Q pre-scaled by 1/sqrt(128).
__global__ __launch_bounds__(512, 2) void qk_gemm(
    const u16* __restrict__ X, const u16* __restrict__ Wq, const u16* __restrict__ Wk,
    const float* __restrict__ bq, const float* __restrict__ bk, u16* __restrict__ Qo,
    u16* __restrict__ Ko) {
  __shared__ __attribute__((aligned(16))) u16 As[32768];  // 4 slots x 256x32, 64 KB
  __shared__ __attribute__((aligned(16))) u16 Bs[32768];  // 64 KB
  const int K = 2048, NT = 64;
  int which = blockIdx.x >> 3;
  int n0 = (blockIdx.x & 7) * 256;
  int m0 = blockIdx.y * 256;
  const u16* W = (which == 0) ? Wq : Wk;
  const float* bias = (which == 0) ? bq : bk;
  u16* out = (which == 0) ? Qo : Ko;
  float scale = (which == 0) ? 0.08838834764831845f : 1.0f;
  int t = threadIdx.x, w = t >> 6, l = t & 63;
  int wm = w >> 2, wn = w & 3;               // wave tile: rows wm*128+[0,128), cols wn*64+[0,64)
  int fr = l & 15, fg = l >> 4;
  int r0 = t >> 2;                           // 0..127; second issue adds 128 rows
  int c0 = (t & 3) ^ ((r0 >> 1) & 3);        // involution slot (row+128 preserves (r>>1)&3)
  const u16* gA = X + (size_t)m0 * K;
  const u16* gB = W + (size_t)n0 * K;
  size_t a0 = (size_t)r0 * K + c0 * 8;
  size_t a1 = a0 + (size_t)128 * K;
  f32x4 zero4 = {0.f, 0.f, 0.f, 0.f};
  f32x4 acc[8][4];
#pragma unroll
  for (int i = 0; i < 8; ++i)
#pragma unroll
    for (int j = 0; j < 4; ++j) acc[i][j] = zero4;
#pragma unroll
  for (int p = 0; p < 2; ++p) {  // prologue: stage tiles 0,1
    u16* sa = As + p * 8192;
    u16* sb = Bs + p * 8192;
    int kk = p * 32;
    gld16(sa + w * 512, gA + a0 + kk);
    gld16(sa + 4096 + w * 512, gA + a1 + kk);
    gld16(sb + w * 512, gB + a0 + kk);
    gld16(sb + 4096 + w * 512, gB + a1 + kk);
  }
  for (int kt = 0; kt < NT; ++kt) {
    int kt2 = (kt + 2 < NT) ? (kt + 2) : (NT - 1);
    u16* sa = As + ((kt + 2) & 3) * 8192;
    u16* sb = Bs + ((kt + 2) & 3) * 8192;
    int kk = kt2 * 32;
    gld16(sa + w * 512, gA + a0 + kk);
    gld16(sa + 4096 + w * 512, gA + a1 + kk);
    gld16(sb + w * 512, gB + a0 + kk);
    gld16(sb + 4096 + w * 512, gB + a1 + kk);
    // 4 own loads/tile; own kt-group is 3rd-newest (<=12 outstanding) -> vmcnt(8)
    asm volatile("s_waitcnt vmcnt(8)\n\ts_barrier" ::: "memory");
    const u16* ca = As + (kt & 3) * 8192;
    const u16* cb = Bs + (kt & 3) * 8192;
    bf16x8 af[8], bfv[4];
#pragma unroll
    for (int i = 0; i < 8; ++i) {
      int ar = wm * 128 + i * 16 + fr;
      af[i] = *(const bf16x8*)&ca[ar * 32 + ((fg ^ ((ar >> 1) & 3)) << 3)];
    }
#pragma unroll
    for (int i = 0; i < 4; ++i) {
      int br = wn * 64 + i * 16 + fr;
      bfv[i] = *(const bf16x8*)&cb[br * 32 + ((fg ^ ((br >> 1) & 3)) << 3)];
    }
    __builtin_amdgcn_s_setprio(1);
#pragma unroll
    for (int mi = 0; mi < 8; ++mi)
#pragma unroll
      for (int ni = 0; ni < 4; ++ni)
        acc[mi][ni] = MFMA(af[mi], bfv[ni], acc[mi][ni]);
    __builtin_amdgcn_s_setprio(0);
  }
#pragma unroll
  for (int mi = 0; mi < 8; ++mi) {
#pragma unroll
    for (int ni = 0; ni < 4; ++ni) {
      int row = m0 + wm * 128 + mi * 16 + (l >> 4) * 4;
      int col = n0 + wn * 64 + ni * 16 + (l & 15);
      float bb = bias[col];
      int h = col >> 7, d = col & 127;
#pragma unroll
      for (int i = 0; i < 4; ++i) {
        int m = row + i;
        int b = m >> 11, s = m & 2047;
        float v = (acc[mi][ni][i] + bb) * scale;
        out[(((size_t)b * 16 + h) * 2048 + s) * 128 + d] = f2bf(v);
      }
    }
  }
}

// ---------------- V projection: 128x128 tile (proven gemm_core), V -> [B,H,D,S] ----------------
__global__ __launch_bounds__(256, 2) void v_gemm(const u16* __restrict__ X,
                                                 const u16* __restrict__ Wv,
                                                 const float* __restrict__ bv,
                                                 u16* __restrict__ Vo) {
  __shared__ __attribute__((aligned(16))) u16 As[16384];
  __shared__ __attribute__((aligned(16))) u16 Bs[16384];
  int n0 = blockIdx.x * 128, m0 = blockIdx.y * 128;
  f32x4 zero4 = {0.f, 0.f, 0.f, 0.f};
  f32x4 acc[4][4];
#pragma unroll
  for (int i = 0; i < 4; ++i)
#pragma unroll
    for (int j = 0; j < 4; ++j) acc[i][j] = zero4;
  gemm_core(X, Wv, As, Bs, m0, n0, acc);
  int t = threadIdx.x, w = t >> 6, l = t & 63;
  int wr = (w >> 1) * 64, wc = (w & 1) * 64;
  // V: transposed write [B,H,D,S]; 4 consecutive s per fragment -> one 8B store
#pragma unroll
  for (int mi = 0; mi < 4; ++mi) {
#pragma unroll
    for (int ni = 0; ni < 4; ++ni) {
      int row = m0 + wr + mi * 16 + (l >> 4) * 4;
      int col = n0 + wc + ni * 16 + (l & 15);
      float bb = bv[col];
      int h = col >> 7, d = col & 127;
      int b = row >> 11, s = row & 2047;
      u32 p0 = (u32)f2bf(acc[mi][ni][0] + bb) | ((u32)f2bf(acc[mi][ni][1] + bb) << 16);
      u32 p1 = (u32)f2bf(acc[mi][ni][2] + bb) | ((u32)f2bf(acc[mi][ni][3] + bb) << 16);
      *(uint2*)&Vo[((size_t)(b * 16 + h) * 128 + d) * 2048 + s] = make_uint2(p0, p1);
    }
  }
}

// ---------------- output projection (fp32 out + bias) ----------------
__global__ __launch_bounds__(256, 2) void oproj_gemm(const u16* __restrict__ A,
                                                     const u16* __restrict__ W,
                                                     const float* __restrict__ bias,
                                                     float* __restrict__ out) {
  __shared__ __attribute__((aligned(16))) u16 As[16384];
  __shared__ __attribute__((aligned(16))) u16 Bs[16384];
  int n0 = blockIdx.x * 128, m0 = blockIdx.y * 128;
  f32x4 zero4 = {0.f, 0.f, 0.f, 0.f};
  f32x4 acc[4][4];
#pragma unroll
  for (int i = 0; i < 4; ++i)
#pragma unroll
    for (int j = 0; j < 4; ++j) acc[i][j] = zero4;
  gemm_core(A, W, As, Bs, m0, n0, acc);
  int t = threadIdx.x, w = t >> 6, l = t & 63;
  int wr = (w >> 1) * 64, wc = (w & 1) * 64;
#pragma unroll
  for (int mi = 0; mi < 4; ++mi) {
#pragma unroll
    for (int ni = 0; ni < 4; ++ni) {
      int row = m0 + wr + mi * 16 + (l >> 4) * 4;
      int col = n0 + wc + ni * 16 + (l & 15);
      float bb = bias[col];
#pragma unroll
      for (int i = 0; i < 4; ++i) out[(size_t)(row + i) * 2048 + col] = acc[mi][ni][i] + bb;
    }
  }
}

// ---------------- flash attention (causal): 8 waves x 16 q-rows, KV tile 64 ----------------
// R14 structure: double-buffer + stage-ahead-1 + counted vmcnt(4), 512 threads,
// MFMA row-sum, plain __expf softmax. P swizzle changed to ^((row>>2)<<5):
// write-side g-groups hit disjoint bank octets (2 lanes/bank = free) while the
// b128 read stays uniformly distributed (8 accesses/bank, optimal).
__global__ __launch_bounds__(512, 4) void attn_fwd(const u16* __restrict__ Q,
                                                   const u16* __restrict__ K,
                                                   const u16* __restrict__ Vt,
                                                   u16* __restrict__ AO) {
  __shared__ __attribute__((aligned(16))) u16 Ks[16384];   // 2 bufs x [64][128], 32 KB
  __shared__ __attribute__((aligned(16))) u16 Vts[16384];  // 2 bufs x [128][64], 32 KB
  __shared__ __attribute__((aligned(16))) u16 Pl[8192];    // 8 waves x [16][64], 16 KB
  const int D = 128;
  int b3 = blockIdx.x;
  int bh = b3 & 31;
  int xq = b3 >> 5;                          // 0..15
  int qt = (xq < 8) ? (15 - xq) : (xq - 8);  // paired: xq and xq+8 sum to const work
  int t = threadIdx.x, w = t >> 6, l = t & 63, g = l >> 4, c = l & 15;
  size_t base = (size_t)bh * 2048 * 128;
  const u16* Vbh = Vt + base;  // [128 d][2048 s]
  int q0 = qt * 128;
  int qrw = q0 + w * 16;  // 16 rows per wave
  // Q fragments in registers; Q pre-scaled by 1/sqrt(D) in qk_gemm
  bf16x8 qf[4];
  {
    const u16* qp = Q + base + (size_t)(qrw + c) * D + g * 8;
#pragma unroll
    for (int ks = 0; ks < 4; ++ks) qf[ks] = *(const bf16x8*)(qp + ks * 32);
  }
  f32x4 zero4 = {0.f, 0.f, 0.f, 0.f};
  f32x4 oacc[8];
#pragma unroll
  for (int i = 0; i < 8; ++i) oacc[i] = zero4;
  f32x4 lacc = zero4;  // row sums via MFMA(P, ones)
  bf16x8 ones;
#pragma unroll
  for (int i = 0; i < 8; ++i) ones[i] = (short)0x3F80;  // bf16 1.0
  float mrow[4];
#pragma unroll
  for (int i = 0; i < 4; ++i) mrow[i] = -1e30f;
  char* pw = (char*)(Pl + w * 1024);  // per-wave [16][64] (2 KB)
  int ktmax = 2 * qt + 1;
  // staging: 4 gld16/thread/tile. K: lane task row=i*32+w*4+(l>>4), slot=l&15
  // holds global chunk slot^(row&7). V: vr=i*64+w*8+(l>>3), vslot=l&7 holds
  // chunk vslot^(vr&7). Dest bases wave-uniform; HW adds lane*16B.
#define STAGE_TILE(BUF, KV0)                                                          \
  {                                                                                   \
    _Pragma("unroll") for (int i = 0; i < 2; ++i) {                                   \
      int row = i * 32 + w * 4 + (l >> 4);                                            \
      int cc = (l & 15) ^ (row & 7);                                                  \
      gld16(Ks + (BUF)*8192 + i * 4096 + w * 512,                                     \
            K + base + (size_t)((KV0) + row) * D + cc * 8);                           \
    }                                                                                 \
    _Pragma("unroll") for (int i = 0; i < 2; ++i) {                                   \
      int vr = i * 64 + w * 8 + (l >> 3);                                             \
      int vslot = (l & 7) ^ ((l >> 3) & 7);                                           \
      gld16(Vts + (BUF)*8192 + i * 4096 + w * 512,                                    \
            Vbh + (size_t)vr * 2048 + (KV0) + vslot * 8);                             \
    }                                                                                 \
  }
  STAGE_TILE(0, 0)  // prologue: tile 0 -> buf 0
  for (int kt = 0; kt <= ktmax; ++kt) {
    int kv0 = kt * 64;
    int ktn = (kt + 1 <= ktmax) ? (kt + 1) : ktmax;  // clamped tail (uniform counts)
    STAGE_TILE((kt + 1) & 1, ktn * 64)
    // own tile-kt loads have exactly 4 newer (kt+1's) outstanding -> vmcnt(4)
    asm volatile("s_waitcnt vmcnt(4)\n\ts_barrier" ::: "memory");
    const u16* Kb = Ks + (kt & 1) * 8192;
    const u16* Vb2 = Vts + (kt & 1) * 8192;
    if (kv0 <= qrw + 15) {  // wave-uniform causal skip (no barriers inside)
      // ---- QK^T from LDS ----
      f32x4 sacc[4];
#pragma unroll
      for (int n = 0; n < 4; ++n) sacc[n] = zero4;
#pragma unroll
      for (int ks = 0; ks < 4; ++ks) {
#pragma unroll
        for (int n = 0; n < 4; ++n) {
          int row = n * 16 + c;
          bf16x8 kf = *(const bf16x8*)&Kb[row * 128 + (((ks * 4 + g) ^ (c & 7)) << 3)];
          sacc[n] = MFMA(qf[ks], kf, sacc[n]);
        }
      }
      float sc[4][4];
#pragma unroll
      for (int n = 0; n < 4; ++n)
#pragma unroll
        for (int i = 0; i < 4; ++i) sc[n][i] = sacc[n][i];
      if (kv0 + 63 > qrw) {  // diagonal region: causal mask
#pragma unroll
        for (int n = 0; n < 4; ++n) {
          int kv = kv0 + n * 16 + c;
#pragma unroll
          for (int i = 0; i < 4; ++i)
            if (kv > qrw + g * 4 + i) sc[n][i] = -1e30f;
        }
      }
      // ---- online softmax: max via 16-lane shuffle reduce; sum via MFMA below ----
      float tmax[4];
#pragma unroll
      for (int i = 0; i < 4; ++i)
        tmax[i] = fmaxf(fmaxf(sc[0][i], sc[1][i]), fmaxf(sc[2][i], sc[3][i]));
#pragma unroll
      for (int x = 1; x < 16; x <<= 1)
#pragma unroll
        for (int i = 0; i < 4; ++i) tmax[i] = fmaxf(tmax[i], __shfl_xor(tmax[i], x));
      float corr[4];
#pragma unroll
      for (int i = 0; i < 4; ++i) {
        float mn = fmaxf(mrow[i], tmax[i]);
        corr[i] = __expf(mrow[i] - mn);
        mrow[i] = mn;
      }
#pragma unroll
      for (int i = 0; i < 4; ++i) lacc[i] *= corr[i];
#pragma unroll
      for (int nf = 0; nf < 8; ++nf)
#pragma unroll
        for (int i = 0; i < 4; ++i) oacc[nf][i] *= corr[i];
      float ps[4][4];
#pragma unroll
      for (int n = 0; n < 4; ++n)
#pragma unroll
        for (int i = 0; i < 4; ++i) ps[n][i] = __expf(sc[n][i] - mrow[i]);
      // ---- P -> per-wave LDS (bank-octet swizzle: ^((row>>2)<<5)) ----
#pragma unroll
      for (int n = 0; n < 4; ++n)
#pragma unroll
        for (int i = 0; i < 4; ++i) {
          int row = g * 4 + i;
          *(u16*)(pw + row * 128 + ((n * 32 + c * 2) ^ ((row >> 2) << 5))) = f2bf(ps[n][i]);
        }
      // ---- PV + row-sum: B-fragments from swizzled Vts; lacc += P . ones ----
#pragma unroll
      for (int ks = 0; ks < 2; ++ks) {
        bf16x8 pf = *(const bf16x8*)(pw + c * 128 + ((ks * 64 + g * 16) ^ ((c >> 2) << 5)));
        lacc = MFMA(pf, ones, lacc);  // lacc[i] += sum_kv P[g*4+i][kv in this ks]
#pragma unroll
        for (int nf = 0; nf < 8; ++nf) {
          bf16x8 vf = *(const bf16x8*)&Vb2[(nf * 16 + c) * 64 + (((ks * 4 + g) ^ (c & 7)) << 3)];
          oacc[nf] = MFMA(pf, vf, oacc[nf]);
        }
      }
    }
    __syncthreads();  // compute-kt LDS reads done before kt+2 overwrites buf[kt&1]
  }
  int b = bh >> 4, h = bh & 15;
#pragma unroll
  for (int nf = 0; nf < 8; ++nf) {
    int d = h * 128 + nf * 16 + c;
#pragma unroll
    for (int i = 0; i < 4; ++i) {
      int q = qrw + g * 4 + i;
      AO[((size_t)b * 2048 + q) * 2048 + d] = f2bf(oacc[nf][i] / lacc[i]);
    }
  }
}

extern "C" void kernel_launch(void* const* d_in, const int* in_sizes, int n_in,
                              void* d_out, int out_size, void* d_ws, size_t ws_size,
                              hipStream_t stream) {
  const float* x = (const float*)d_in[0];
  const float* Wq = (const float*)d_in[1];
  const float* bq = (const float*)d_in[2];
  const float* Wk = (const float*)d_in[3];
  const float* bk = (const float*)d_in[4];
  const float* Wv = (const float*)d_in[5];
  const float* bv = (const float*)d_in[6];
  const float* Wo = (const float*)d_in[7];
  const float* bo = (const float*)d_in[8];
  float* out = (float*)d_out;

  u16* xb = (u16*)d_ws;
  u16* Wqb = xb + 8388608;
  u16* Wkb = Wqb + 4194304;
  u16* Wvb = Wkb + 4194304;
  u16* Wob = Wvb + 4194304;
  u16* Qb = Wob + 4194304;
  u16* Kb = Qb + 8388608;
  u16* Vb = Kb + 8388608;  // [B,H,D,S] transposed
  u16* AOb = xb;           // alias: x_bf16 dead after projections

  cvt_all<<<24576, 256, 0, stream>>>(x, Wq, Wk, Wv, Wo, (uint2*)d_ws);
  qk_gemm<<<dim3(16, 16), 512, 0, stream>>>(xb, Wqb, Wkb, bq, bk, Qb, Kb);
  v_gemm<<<dim3(16, 32), 256, 0, stream>>>(xb, Wvb, bv, Vb);
  attn_fwd<<<512, 512, 0, stream>>>(Qb, Kb, Vb, AOb);
  oproj_gemm<<<dim3(16, 32), 256, 0, stream>>>(AOb, Wob, bo, out);
}